// Round 7
// baseline (77.228 us; speedup 1.0000x reference)
//
#include <hip/hip_runtime.h>
#include <hip/hip_bf16.h>
#include <math.h>

#define CIN    1024
#define S_TOT  400
#define COUT   255
#define NCH    85
#define NIMG   64
#define SB     16            // spatial columns per block (one MFMA N-tile)
#define NTHR   256

// LDS: X panel for one K-half: [16 s][64 g] x 16B = 16384 B
#define LDS_BYTES 16384

typedef __attribute__((ext_vector_type(8))) short bf16x8;
typedef __attribute__((ext_vector_type(4))) float f32x4;

// 16B store with 4B alignment guarantee (out row stride 85 floats)
struct __attribute__((aligned(4))) f4u { float x, y, z, w; };

// X LDS granule (s_local, g_local). Row = s (1024B stride); XOR-swizzle by
// (s>>1) — 2-way on reads (free), verified ~0 conflicts rounds 3-6.
__device__ __forceinline__ int xOff(int s, int gl) {
    return (s << 10) + ((gl << 4) ^ (((s >> 1) & 7) << 4));
}

__device__ __forceinline__ unsigned pk2(float a, float b) {
    __hip_bfloat162 h;
    h.x = __float2bfloat16(a);
    h.y = __float2bfloat16(b);
    return *reinterpret_cast<unsigned*>(&h);
}

__device__ __forceinline__ float sigmoidf_(float v) {
    return 1.0f / (1.0f + expf(-v));
}

// ---- pre-kernel: W fp32 -> bf16, granule-major [g][co][8k] (512 KiB) ----
__global__ __launch_bounds__(256) void w_pre2(const float* __restrict__ w,
                                              unsigned short* __restrict__ wbf) {
    int gidx = blockIdx.x * 256 + threadIdx.x;
    int co = gidx & 255;          // fastest -> coalesced 16B writes
    int g  = gidx >> 8;           // 0..127 (k = g*8)
    union { unsigned short u[8]; bf16x8 v; } pk;
    if (co < COUT) {
        const float* src = w + (size_t)co * CIN + g * 8;
        #pragma unroll
        for (int j = 0; j < 8; ++j) {
            __hip_bfloat16 h = __float2bfloat16(src[j]);
            pk.u[j] = *reinterpret_cast<unsigned short*>(&h);
        }
    } else {
        #pragma unroll
        for (int j = 0; j < 8; ++j) pk.u[j] = 0;    // pad co=255
    }
    *reinterpret_cast<bf16x8*>((char*)wbf + ((size_t)(g << 8) + co) * 16) = pk.v;
}

// ---- main: block = 16 s x 1 img, all 255 co; A from L2, B from LDS ----
__global__ __launch_bounds__(NTHR, 4) void yolo_mfma3(
    const float* __restrict__ xin,
    const unsigned short* __restrict__ wbf,
    const float* __restrict__ bias,
    float* __restrict__ out)
{
    __shared__ __align__(16) char smem[LDS_BYTES];

    const int sb  = blockIdx.x * SB;
    const int n   = blockIdx.y;
    const int tid = threadIdx.x;
    const int lane = tid & 63;
    const int wid  = tid >> 6;
    const int llo  = lane & 15;
    const int lhi  = lane >> 4;

    // staging unit: gl = tid>>2 (k-granule 0..63), sq = tid&3 (s-quad 0..3)
    // -> lanes 0-3 read 64B contiguous per row j.
    const int gl_u = tid >> 2;
    const int sq_u = tid & 3;

    f32x4 acc[4] = {};

    for (int h = 0; h < 2; ++h) {
        if (h) __syncthreads();            // protect smem from in-flight reads

        // ---- stage X K-half h: 8 float4 rows -> 4 swizzled bf16x8 granules ----
        {
            const float* src = xin
                + ((size_t)n * CIN + h * 512 + gl_u * 8) * S_TOT
                + sb + 4 * sq_u;
            float4 cu[8];
            #pragma unroll
            for (int j = 0; j < 8; ++j) cu[j] = *(const float4*)(src + j * S_TOT);
            // row r (s = 4*sq_u + r): 8 k-values = component r of the 8 rows
            union { unsigned u[4]; bf16x8 v; } rr;
            #pragma unroll
            for (int r = 0; r < 4; ++r) {
                const float* cf = (const float*)cu;   // cu[j][r] = cf[4*j + r]
                #pragma unroll
                for (int j = 0; j < 4; ++j)
                    rr.u[j] = pk2(cf[8 * j + r], cf[8 * j + 4 + r]);
                *(bf16x8*)(smem + xOff(4 * sq_u + r, gl_u)) = rr.v;
            }
        }
        __syncthreads();

        // ---- 16 barrier-free MFMA K-steps; A straight from L2-resident wbf ----
        #pragma unroll 4
        for (int kk = 0; kk < 16; ++kk) {
            const int gA = (h * 16 + kk) * 4 + lhi;   // global k-granule
            const int gl = kk * 4 + lhi;              // LDS k-granule
            bf16x8 b = *(bf16x8*)(smem + xOff(llo, gl));
            #pragma unroll
            for (int mi = 0; mi < 4; ++mi) {
                const int co = wid * 64 + mi * 16 + llo;
                bf16x8 a = *(const bf16x8*)((const char*)wbf
                                            + ((size_t)(gA << 8) + co) * 16);
                acc[mi] = __builtin_amdgcn_mfma_f32_16x16x32_bf16(a, b, acc[mi], 0, 0, 0);
            }
        }
    }

    // ---- fused YOLO epilogue: 16B stores of 4 consecutive co ----
    const float anchW[3] = {116.0f, 156.0f, 373.0f};
    const float anchH[3] = {90.0f, 198.0f, 326.0f};

    const int s = sb + llo;
    const float sx = (float)(s % 20);
    const float sy = (float)(s / 20);

    #pragma unroll
    for (int mi = 0; mi < 4; ++mi) {
        const int co0 = wid * 64 + mi * 16 + lhi * 4;
        const int aW  = co0 / NCH;
        const int c0  = co0 - aW * NCH;
        const bool whole = (c0 <= NCH - 4) && (co0 + 3 < COUT);
        float bv[4];
        #pragma unroll
        for (int r = 0; r < 4; ++r)
            bv[r] = (co0 + r < COUT) ? bias[co0 + r] : 0.0f;

        if (whole) {
            float r4[4];
            #pragma unroll
            for (int r = 0; r < 4; ++r) {
                const int c = c0 + r;
                const float v = acc[mi][r] + bv[r];
                float res;
                if (c == 0)      res = (sigmoidf_(v) + sx) * 32.0f;
                else if (c == 1) res = (sigmoidf_(v) + sy) * 32.0f;
                else if (c == 2) res = expf(v) * anchW[aW];
                else if (c == 3) res = expf(v) * anchH[aW];
                else             res = sigmoidf_(v);
                r4[r] = res;
            }
            f4u* p = (f4u*)(out + (size_t)n * 102000 + aW * 34000 + s * 85 + c0);
            f4u val = {r4[0], r4[1], r4[2], r4[3]};
            *p = val;
        } else {
            #pragma unroll
            for (int r = 0; r < 4; ++r) {
                const int co = co0 + r;
                if (co < COUT) {
                    const int a2 = co / NCH;
                    const int c  = co - a2 * NCH;
                    const float v = acc[mi][r] + bv[r];
                    float res;
                    if (c == 0)      res = (sigmoidf_(v) + sx) * 32.0f;
                    else if (c == 1) res = (sigmoidf_(v) + sy) * 32.0f;
                    else if (c == 2) res = expf(v) * anchW[a2];
                    else if (c == 3) res = expf(v) * anchH[a2];
                    else             res = sigmoidf_(v);
                    out[(size_t)n * 102000 + a2 * 34000 + s * 85 + c] = res;
                }
            }
        }
    }
}

extern "C" void kernel_launch(void* const* d_in, const int* in_sizes, int n_in,
                              void* d_out, int out_size, void* d_ws, size_t ws_size,
                              hipStream_t stream) {
    const float* xin  = (const float*)d_in[0];
    const float* w    = (const float*)d_in[1];
    const float* bias = (const float*)d_in[2];
    float* out = (float*)d_out;
    unsigned short* wbf = (unsigned short*)d_ws;   // 512 KiB granule-major W

    w_pre2<<<128, 256, 0, stream>>>(w, wbf);
    yolo_mfma3<<<dim3(S_TOT / SB, NIMG), NTHR, 0, stream>>>(xin, wbf, bias, out);
}

// Round 8
// 72.503 us; speedup vs baseline: 1.0652x; 1.0652x over previous
//
#include <hip/hip_runtime.h>
#include <hip/hip_bf16.h>
#include <math.h>

#define CIN    1024
#define S_TOT  400
#define COUT   255
#define NCH    85
#define NIMG   64
#define SB     16            // spatial columns per block (one MFMA N-tile)
#define NTHR   256

// LDS: full X tile [16 s][128 g] x 16B = 32768 B, staged ONCE per block
#define LDS_BYTES 32768

typedef __attribute__((ext_vector_type(8))) short bf16x8;
typedef __attribute__((ext_vector_type(4))) float f32x4;

// 16B store with 4B alignment guarantee (out row stride 85 floats)
struct __attribute__((aligned(4))) f4u { float x, y, z, w; };

// X LDS granule (s, g): row = s (2048B stride), XOR-swizzle by (s>>1) —
// ~2-way on both staged writes and fragment reads (measured ~0 conflicts).
__device__ __forceinline__ int xOff(int s, int g) {
    return (s << 11) + ((g << 4) ^ (((s >> 1) & 7) << 4));
}

__device__ __forceinline__ unsigned pk2(float a, float b) {
    __hip_bfloat162 h;
    h.x = __float2bfloat16(a);
    h.y = __float2bfloat16(b);
    return *reinterpret_cast<unsigned*>(&h);
}

__device__ __forceinline__ float sigmoidf_(float v) {
    return 1.0f / (1.0f + expf(-v));
}

// ---- pre-kernel: W fp32 -> bf16, granule-major [g][co][8k] (512 KiB) ----
__global__ __launch_bounds__(256) void w_pre2(const float* __restrict__ w,
                                              unsigned short* __restrict__ wbf) {
    int gidx = blockIdx.x * 256 + threadIdx.x;
    int co = gidx & 255;          // fastest -> coalesced 16B writes
    int g  = gidx >> 8;           // 0..127 (k = g*8)
    union { unsigned short u[8]; bf16x8 v; } pk;
    if (co < COUT) {
        const float* src = w + (size_t)co * CIN + g * 8;
        #pragma unroll
        for (int j = 0; j < 8; ++j) {
            __hip_bfloat16 h = __float2bfloat16(src[j]);
            pk.u[j] = *reinterpret_cast<unsigned short*>(&h);
        }
    } else {
        #pragma unroll
        for (int j = 0; j < 8; ++j) pk.u[j] = 0;    // pad co=255
    }
    *reinterpret_cast<bf16x8*>((char*)wbf + ((size_t)(g << 8) + co) * 16) = pk.v;
}

// ---- main: block = 16 s x 1 img, all 255 co; ONE barrier, then 4 waves
//      run 32 independent K-steps each (A from L2, B from LDS) ----
__global__ __launch_bounds__(NTHR, 4) void yolo_mfma4(
    const float* __restrict__ xin,
    const unsigned short* __restrict__ wbf,
    const float* __restrict__ bias,
    float* __restrict__ out)
{
    __shared__ __align__(16) char smem[LDS_BYTES];

    const int sb  = blockIdx.x * SB;
    const int n   = blockIdx.y;
    const int tid = threadIdx.x;
    const int lane = tid & 63;
    const int wid  = tid >> 6;
    const int llo  = lane & 15;
    const int lhi  = lane >> 4;

    // ---- stage the whole X tile (16 s x 1024 k) once: 512 units (g, s-quad),
    //      2 per thread; each unit = 8 float4 rows -> 4 swizzled granules ----
    #pragma unroll
    for (int p = 0; p < 2; ++p) {
        const int u   = p * 256 + tid;
        const int g_u = u >> 2;        // k-granule 0..127
        const int sq  = u & 3;         // s-quad 0..3
        const float* src = xin + ((size_t)n * CIN + g_u * 8) * S_TOT + sb + 4 * sq;
        float4 cu[8];
        #pragma unroll
        for (int j = 0; j < 8; ++j) cu[j] = *(const float4*)(src + j * S_TOT);
        const float* cf = (const float*)cu;    // cu[j][r] = cf[4*j + r]
        #pragma unroll
        for (int r = 0; r < 4; ++r) {
            union { unsigned u4[4]; bf16x8 v; } rr;
            #pragma unroll
            for (int j = 0; j < 4; ++j)
                rr.u4[j] = pk2(cf[8 * j + r], cf[8 * j + 4 + r]);
            *(bf16x8*)(smem + xOff(4 * sq + r, g_u)) = rr.v;
        }
    }
    __syncthreads();   // the ONLY barrier in the kernel

    // ---- 32 barrier-free K-steps per wave, manual 1-deep prefetch ----
    f32x4 acc[4] = {};
    const char* wb = (const char*)wbf;
    const int coB = wid * 64 + llo;

    bf16x8 b_c = *(bf16x8*)(smem + xOff(llo, lhi));
    bf16x8 a_c[4];
    #pragma unroll
    for (int mi = 0; mi < 4; ++mi)
        a_c[mi] = *(const bf16x8*)(wb + ((size_t)((lhi << 8) + coB + mi * 16)) * 16);

    #pragma unroll 4
    for (int kk = 0; kk < 31; ++kk) {
        const int gn = (kk + 1) * 4 + lhi;
        bf16x8 b_n = *(bf16x8*)(smem + xOff(llo, gn));
        bf16x8 a_n[4];
        #pragma unroll
        for (int mi = 0; mi < 4; ++mi)
            a_n[mi] = *(const bf16x8*)(wb + ((size_t)((gn << 8) + coB + mi * 16)) * 16);
        #pragma unroll
        for (int mi = 0; mi < 4; ++mi)
            acc[mi] = __builtin_amdgcn_mfma_f32_16x16x32_bf16(a_c[mi], b_c, acc[mi], 0, 0, 0);
        b_c = b_n;
        #pragma unroll
        for (int mi = 0; mi < 4; ++mi) a_c[mi] = a_n[mi];
    }
    #pragma unroll
    for (int mi = 0; mi < 4; ++mi)
        acc[mi] = __builtin_amdgcn_mfma_f32_16x16x32_bf16(a_c[mi], b_c, acc[mi], 0, 0, 0);

    // ---- fused YOLO epilogue: 16B stores of 4 consecutive co ----
    const float anchW[3] = {116.0f, 156.0f, 373.0f};
    const float anchH[3] = {90.0f, 198.0f, 326.0f};

    const int s = sb + llo;
    const float sx = (float)(s % 20);
    const float sy = (float)(s / 20);

    #pragma unroll
    for (int mi = 0; mi < 4; ++mi) {
        const int co0 = wid * 64 + mi * 16 + lhi * 4;
        const int aW  = co0 / NCH;
        const int c0  = co0 - aW * NCH;
        const bool whole = (c0 <= NCH - 4) && (co0 + 3 < COUT);
        float bv[4];
        #pragma unroll
        for (int r = 0; r < 4; ++r)
            bv[r] = (co0 + r < COUT) ? bias[co0 + r] : 0.0f;

        if (whole) {
            float r4[4];
            #pragma unroll
            for (int r = 0; r < 4; ++r) {
                const int c = c0 + r;
                const float v = acc[mi][r] + bv[r];
                float res;
                if (c == 0)      res = (sigmoidf_(v) + sx) * 32.0f;
                else if (c == 1) res = (sigmoidf_(v) + sy) * 32.0f;
                else if (c == 2) res = expf(v) * anchW[aW];
                else if (c == 3) res = expf(v) * anchH[aW];
                else             res = sigmoidf_(v);
                r4[r] = res;
            }
            f4u* p = (f4u*)(out + (size_t)n * 102000 + aW * 34000 + s * 85 + c0);
            f4u val = {r4[0], r4[1], r4[2], r4[3]};
            *p = val;
        } else {
            #pragma unroll
            for (int r = 0; r < 4; ++r) {
                const int co = co0 + r;
                if (co < COUT) {
                    const int a2 = co / NCH;
                    const int c  = co - a2 * NCH;
                    const float v = acc[mi][r] + bv[r];
                    float res;
                    if (c == 0)      res = (sigmoidf_(v) + sx) * 32.0f;
                    else if (c == 1) res = (sigmoidf_(v) + sy) * 32.0f;
                    else if (c == 2) res = expf(v) * anchW[a2];
                    else if (c == 3) res = expf(v) * anchH[a2];
                    else             res = sigmoidf_(v);
                    out[(size_t)n * 102000 + a2 * 34000 + s * 85 + c] = res;
                }
            }
        }
    }
}

extern "C" void kernel_launch(void* const* d_in, const int* in_sizes, int n_in,
                              void* d_out, int out_size, void* d_ws, size_t ws_size,
                              hipStream_t stream) {
    const float* xin  = (const float*)d_in[0];
    const float* w    = (const float*)d_in[1];
    const float* bias = (const float*)d_in[2];
    float* out = (float*)d_out;
    unsigned short* wbf = (unsigned short*)d_ws;   // 512 KiB granule-major W

    w_pre2<<<128, 256, 0, stream>>>(w, wbf);
    yolo_mfma4<<<dim3(S_TOT / SB, NIMG), NTHR, 0, stream>>>(xin, wbf, bias, out);
}